// Round 1
// baseline (459.634 us; speedup 1.0000x reference)
//
#include <hip/hip_runtime.h>
#include <math.h>

// Problem constants (from setup_inputs: bs=16, nq=550, nc=91, nt=48, group_num=11)
#define BS 16
#define NQ 550
#define NC 91
#define NT 48
#define GN 11
#define GQ 50                 // queries per group = 550/11
#define NTOT (BS * NT)        // 768 targets across batches
#define NROW 48               // transposed LSA rows (targets)
#define MCOL 50               // transposed LSA cols (queries)
#define NPAIR (GN * NT)       // 528 matched pairs per batch

// ---------- Kernel 1: cost matrix ----------
// All f32 arithmetic uses __f*_rn intrinsics in the reference's association
// order to avoid FMA contraction (hipcc default -ffp-contract=fast would
// change bits vs the numpy reference). exp/log evaluated in double, rounded
// once -> correctly-rounded f32 (<=1 ulp from any faithful libm).

__device__ __forceinline__ float sigmoid_f32(float x) {
    double e = exp(-(double)x);
    return (float)(1.0 / (1.0 + e));
}
__device__ __forceinline__ float log_f32(float x) {
    return (float)log((double)x);
}

__global__ __launch_bounds__(256) void cost_kernel(
    const float* __restrict__ logits,   // [BS*NQ, NC]
    const float* __restrict__ pboxes,   // [BS*NQ, 6]
    const int*   __restrict__ labels,   // [NTOT]
    const float* __restrict__ tboxes,   // [NTOT, 6]
    float*       __restrict__ C)        // [BS*NQ, NTOT]
{
    long idx = (long)blockIdx.x * 256 + threadIdx.x;
    if (idx >= (long)BS * NQ * NTOT) return;
    int t = (int)(idx % NTOT);
    int p = (int)(idx / NTOT);

    const float* pb = pboxes + (long)p * 6;
    float pcx = pb[0], pcy = pb[1], pl = pb[2], pr = pb[3], ptt = pb[4], pbo = pb[5];
    const float* tb = tboxes + (long)t * 6;
    float tcx = tb[0], tcy = tb[1], tl = tb[2], tr = tb[3], ttt = tb[4], tbo = tb[5];

    // cost_3dcenter = |dcx| + |dcy|
    float c3d = __fadd_rn(fabsf(__fsub_rn(pcx, tcx)), fabsf(__fsub_rn(pcy, tcy)));
    // cost_bbox = ((|dl|+|dr|)+|dt|)+|db|  (numpy sequential sum order)
    float cbb = __fadd_rn(
                  __fadd_rn(
                    __fadd_rn(fabsf(__fsub_rn(pl, tl)), fabsf(__fsub_rn(pr, tr))),
                    fabsf(__fsub_rn(ptt, ttt))),
                  fabsf(__fsub_rn(pbo, tbo)));

    // cxcylrtb -> xyxy
    float px1 = __fsub_rn(pcx, pl), py1 = __fsub_rn(pcy, ptt);
    float px2 = __fadd_rn(pcx, pr), py2 = __fadd_rn(pcy, pbo);
    float tx1 = __fsub_rn(tcx, tl), ty1 = __fsub_rn(tcy, ttt);
    float tx2 = __fadd_rn(tcx, tr), ty2 = __fadd_rn(tcy, tbo);

    float area1 = __fmul_rn(__fsub_rn(px2, px1), __fsub_rn(py2, py1));
    float area2 = __fmul_rn(__fsub_rn(tx2, tx1), __fsub_rn(ty2, ty1));
    float ltx = fmaxf(px1, tx1), lty = fmaxf(py1, ty1);
    float rbx = fminf(px2, tx2), rby = fminf(py2, ty2);
    float wx = fmaxf(__fsub_rn(rbx, ltx), 0.0f);
    float wy = fmaxf(__fsub_rn(rby, lty), 0.0f);
    float inter = __fmul_rn(wx, wy);
    float uni = __fsub_rn(__fadd_rn(area1, area2), inter);   // (a1+a2)-inter
    float iou = __fdiv_rn(inter, uni);
    float ex1 = fminf(px1, tx1), ey1 = fminf(py1, ty1);
    float ex2 = fmaxf(px2, tx2), ey2 = fmaxf(py2, ty2);
    float ew = fmaxf(__fsub_rn(ex2, ex1), 0.0f);
    float eh = fmaxf(__fsub_rn(ey2, ey1), 0.0f);
    float earea = __fmul_rn(ew, eh);
    float giou = __fsub_rn(iou, __fdiv_rn(__fsub_rn(earea, uni), earea));
    float cgiou = -giou;

    // focal-style class cost for class = labels[t]
    int c = labels[t];
    float x = logits[(long)p * NC + c];
    float prob = sigmoid_f32(x);
    float q = __fsub_rn(1.0f, prob);
    const float EPSF = 1e-8f;                      // f32(1e-8)
    float lneg = log_f32(__fadd_rn(q, EPSF));      // log(1-p+eps)
    float lpos = log_f32(__fadd_rn(prob, EPSF));   // log(p+eps)
    float p2 = __fmul_rn(prob, prob);              // p**2.0
    float q2 = __fmul_rn(q, q);                    // (1-p)**2.0
    float neg = __fmul_rn(__fmul_rn(0.75f, p2), -lneg);  // (1-ALPHA)*p^2*(-log(1-p+eps))
    float pos = __fmul_rn(__fmul_rn(0.25f, q2), -lpos);  // ALPHA*(1-p)^2*(-log(p+eps))
    float cclass = __fsub_rn(pos, neg);

    // C = ((5*bbox + 10*c3d) + 2*class) + 2*giou   (left-assoc f32)
    float out = __fmul_rn(5.0f, cbb);
    out = __fadd_rn(out, __fmul_rn(10.0f, c3d));
    out = __fadd_rn(out, __fmul_rn(2.0f, cclass));
    out = __fadd_rn(out, __fmul_rn(2.0f, cgiou));
    C[idx] = out;
}

// ---------- Kernel 2: Jonker-Volgenant LSA, one 50x48 problem per wave ----------
// Reference transposes (50>48) -> solve n=48 rows (targets) x m=50 cols (queries).
// f64 throughout, op-order identical to the numpy reference -> bit-exact
// decisions given identical f32 C. Lane l owns column l (l in [0,50]).

__global__ __launch_bounds__(64) void lsa_kernel(
    const float* __restrict__ C,   // [BS*NQ, NTOT]
    float*       __restrict__ pi,  // [BS, NPAIR]
    float*       __restrict__ ti)  // [BS, NPAIR]
{
    const int blk = blockIdx.x;          // 0..175
    const int b = blk / GN, g = blk % GN;
    const int lane = threadIdx.x;        // 0..63

    __shared__ double cost[NROW * MCOL]; // [target i][query j]
    __shared__ double u[NROW + 1];
    __shared__ int pcol[MCOL + 1];       // column -> assigned row (1-based), 0 = free

    // Load group block, transposed, upcast to f64 (same values the reference
    // upcasts from the f32 C).
    for (int k = lane; k < NROW * MCOL; k += 64) {
        int i = k / MCOL, j = k % MCOL;
        cost[k] = (double)C[((long)(b * NQ + g * GQ + j)) * NTOT + (b * NT + i)];
    }
    for (int k = lane; k <= NROW; k += 64) u[k] = 0.0;
    if (lane <= MCOL) pcol[lane] = 0;
    double v_l = 0.0;   // v[lane] for lane in [0,50]
    int way_l = 0;      // way[lane]
    const double INF = __builtin_inf();
    __syncthreads();

    const bool incol = (lane >= 1 && lane <= MCOL);

    for (int i = 1; i <= NROW; ++i) {
        if (lane == 0) pcol[0] = i;
        double minv_l = INF;
        bool used_l = false;
        int j0 = 0;
        __syncthreads();

        // shortest augmenting path
        for (int guard = 0; guard <= MCOL; ++guard) {
            if (lane == j0) used_l = true;
            int i0 = pcol[j0];          // broadcast LDS read
            double u_i0 = u[i0];

            bool free_l = incol && !used_l;
            double val = INF;
            int idxl = 1023;
            if (free_l) {
                double cur = cost[(i0 - 1) * MCOL + (lane - 1)] - u_i0 - v_l;
                if (cur < minv_l) { minv_l = cur; way_l = j0; }
                val = minv_l;
                idxl = lane;
            }
            // min-reduce (value, lowest index on ties) across 64 lanes
            double bestv = val; int bestj = idxl;
            for (int off = 32; off > 0; off >>= 1) {
                double ov = __shfl_xor(bestv, off, 64);
                int oj = __shfl_xor(bestj, off, 64);
                if (ov < bestv || (ov == bestv && oj < bestj)) { bestv = ov; bestj = oj; }
            }
            double delta = bestv;
            int j1 = bestj;

            if (used_l && (incol || lane == 0)) {
                v_l -= delta;
                int row = pcol[lane];   // distinct rows across used lanes
                u[row] += delta;
            } else if (incol) {
                minv_l -= delta;
            }
            j0 = j1;
            __syncthreads();
            if (pcol[j0] == 0) break;
        }

        // augment: p[j0] = p[way[j0]] back-walk
        int j = j0;
        while (j != 0) {
            int wj = __shfl(way_l, j, 64);   // way[j] (frozen when j became used)
            int pwj = pcol[wj];
            __syncthreads();
            if (lane == 0) pcol[j] = pwj;
            __syncthreads();
            j = wj;
        }
    }

    // Extract: columns j=1..50 ascending with pcol[j]!=0 gives queries already
    // sorted (matches argsort of unique ascending rows).
    if (lane == 0) {
        int k = 0;
        float* pib = pi + ((long)b * NPAIR + (long)g * NT);
        float* tib = ti + ((long)b * NPAIR + (long)g * NT);
        for (int j = 1; j <= MCOL; ++j) {
            int pj = pcol[j];
            if (pj != 0) {
                pib[k] = (float)(g * GQ + (j - 1));
                tib[k] = (float)(pj - 1);
                ++k;
            }
        }
    }
}

extern "C" void kernel_launch(void* const* d_in, const int* in_sizes, int n_in,
                              void* d_out, int out_size, void* d_ws, size_t ws_size,
                              hipStream_t stream) {
    const float* logits = (const float*)d_in[0];   // [16,550,91] f32
    const float* pboxes = (const float*)d_in[1];   // [16,550,6] f32
    const int*   labels = (const int*)d_in[2];     // [16,48] i32
    const float* tboxes = (const float*)d_in[3];   // [16,48,6] f32
    // d_in[4] = group_num (fixed 11, compiled in)

    float* out = (float*)d_out;
    float* C  = out;                               // 16*550*768 = 6,758,400
    float* pi = out + (long)BS * NQ * NTOT;        // 16*528
    float* ti = pi + (long)BS * NPAIR;             // 16*528

    long total = (long)BS * NQ * NTOT;
    int blocks = (int)((total + 255) / 256);
    cost_kernel<<<blocks, 256, 0, stream>>>(logits, pboxes, labels, tboxes, C);
    lsa_kernel<<<BS * GN, 64, 0, stream>>>(C, pi, ti);
}

// Round 2
// 212.877 us; speedup vs baseline: 2.1592x; 2.1592x over previous
//
#include <hip/hip_runtime.h>
#include <math.h>

// Problem constants (setup_inputs: bs=16, nq=550, nc=91, nt=48, group_num=11)
#define BS 16
#define NQ 550
#define NC 91
#define NT 48
#define GN 11
#define GQ 50                 // queries per group
#define NTOT (BS * NT)        // 768
#define NROW 48               // LSA rows (targets) after reference transpose
#define MCOL 50               // LSA cols (queries)
#define NPAIR (GN * NT)       // 528

// ---------------- focal (class) cost: exact same f64->f32 math as round 1 ----
__device__ __forceinline__ float sigmoid_f32(float x) {
    double e = exp(-(double)x);
    return (float)(1.0 / (1.0 + e));
}
__device__ __forceinline__ float log_f32(float x) {
    return (float)log((double)x);
}
__device__ __forceinline__ float focal_cost(float x) {
    float prob = sigmoid_f32(x);
    float q = __fsub_rn(1.0f, prob);
    const float EPSF = 1e-8f;
    float lneg = log_f32(__fadd_rn(q, EPSF));
    float lpos = log_f32(__fadd_rn(prob, EPSF));
    float p2 = __fmul_rn(prob, prob);
    float q2 = __fmul_rn(q, q);
    float neg = __fmul_rn(__fmul_rn(0.75f, p2), -lneg);
    float pos = __fmul_rn(__fmul_rn(0.25f, q2), -lpos);
    return __fsub_rn(pos, neg);
}

// Table: tab[p*NC + c] = focal cost. Only 800,800 transcendental triples
// instead of 6.76M (labels repeat classes ~8.4x).
__global__ __launch_bounds__(256) void focal_table_kernel(
    const float* __restrict__ logits, float* __restrict__ tab) {
    int idx = blockIdx.x * 256 + threadIdx.x;
    if (idx >= BS * NQ * NC) return;
    tab[idx] = focal_cost(logits[idx]);
}

// ---------------- cost matrix ----------------
// f32 ops via __f*_rn in reference association order (no FMA contraction).
template <bool USE_TAB>
__global__ __launch_bounds__(256) void cost_kernel(
    const float* __restrict__ tab,      // focal table (if USE_TAB)
    const float* __restrict__ logits,   // [BS*NQ, NC] (if !USE_TAB)
    const float* __restrict__ pboxes,   // [BS*NQ, 6]
    const int*   __restrict__ labels,   // [NTOT]
    const float* __restrict__ tboxes,   // [NTOT, 6]
    float*       __restrict__ C)        // [BS*NQ, NTOT]
{
    long idx = (long)blockIdx.x * 256 + threadIdx.x;
    if (idx >= (long)BS * NQ * NTOT) return;
    int t = (int)(idx % NTOT);
    int p = (int)(idx / NTOT);

    const float* pb = pboxes + (long)p * 6;
    float pcx = pb[0], pcy = pb[1], pl = pb[2], pr = pb[3], ptt = pb[4], pbo = pb[5];
    const float* tb = tboxes + (long)t * 6;
    float tcx = tb[0], tcy = tb[1], tl = tb[2], tr = tb[3], ttt = tb[4], tbo = tb[5];

    float c3d = __fadd_rn(fabsf(__fsub_rn(pcx, tcx)), fabsf(__fsub_rn(pcy, tcy)));
    float cbb = __fadd_rn(
                  __fadd_rn(
                    __fadd_rn(fabsf(__fsub_rn(pl, tl)), fabsf(__fsub_rn(pr, tr))),
                    fabsf(__fsub_rn(ptt, ttt))),
                  fabsf(__fsub_rn(pbo, tbo)));

    float px1 = __fsub_rn(pcx, pl), py1 = __fsub_rn(pcy, ptt);
    float px2 = __fadd_rn(pcx, pr), py2 = __fadd_rn(pcy, pbo);
    float tx1 = __fsub_rn(tcx, tl), ty1 = __fsub_rn(tcy, ttt);
    float tx2 = __fadd_rn(tcx, tr), ty2 = __fadd_rn(tcy, tbo);

    float area1 = __fmul_rn(__fsub_rn(px2, px1), __fsub_rn(py2, py1));
    float area2 = __fmul_rn(__fsub_rn(tx2, tx1), __fsub_rn(ty2, ty1));
    float ltx = fmaxf(px1, tx1), lty = fmaxf(py1, ty1);
    float rbx = fminf(px2, tx2), rby = fminf(py2, ty2);
    float wx = fmaxf(__fsub_rn(rbx, ltx), 0.0f);
    float wy = fmaxf(__fsub_rn(rby, lty), 0.0f);
    float inter = __fmul_rn(wx, wy);
    float uni = __fsub_rn(__fadd_rn(area1, area2), inter);
    float iou = __fdiv_rn(inter, uni);
    float ex1 = fminf(px1, tx1), ey1 = fminf(py1, ty1);
    float ex2 = fmaxf(px2, tx2), ey2 = fmaxf(py2, ty2);
    float ew = fmaxf(__fsub_rn(ex2, ex1), 0.0f);
    float eh = fmaxf(__fsub_rn(ey2, ey1), 0.0f);
    float earea = __fmul_rn(ew, eh);
    float giou = __fsub_rn(iou, __fdiv_rn(__fsub_rn(earea, uni), earea));
    float cgiou = -giou;

    int c = labels[t];
    float cclass;
    if (USE_TAB) {
        cclass = tab[(long)p * NC + c];
    } else {
        cclass = focal_cost(logits[(long)p * NC + c]);
    }

    float out = __fmul_rn(5.0f, cbb);
    out = __fadd_rn(out, __fmul_rn(10.0f, c3d));
    out = __fadd_rn(out, __fmul_rn(2.0f, cclass));
    out = __fadd_rn(out, __fmul_rn(2.0f, cgiou));
    C[idx] = out;
}

// ---------------- LSA: JV shortest augmenting path, one problem per wave ----
// All cross-lane state in registers: lane j in [0,50] holds column state
// {pcol[j], urow[j]=u[pcol[j]], v[j], minv[j], way[j], used[j]}. u[] is fully
// virtualized into urow (rows only get += delta while their column is used;
// the back-walk moves (pcol,urow) together so the invariant survives).
// Reads use v_readlane (wave-uniform index); argmin via DPP f64 min-reduce +
// ballot/ctz (lowest lane = np.argmin tie-break). All f64 ops are the same
// IEEE ops in the same order as the numpy reference -> bit-exact decisions.

__device__ __forceinline__ double readlane_f64(double x, int l) {
    long long b = __double_as_longlong(x);
    int lo = __builtin_amdgcn_readlane((int)(b & 0xffffffffLL), l);
    int hi = __builtin_amdgcn_readlane((int)(b >> 32), l);
    return __longlong_as_double(((long long)hi << 32) | (unsigned int)lo);
}

template <int CTRL, int RM>
__device__ __forceinline__ double dpp_min_f64(double x) {
    long long b = __double_as_longlong(x);
    int lo = (int)(b & 0xffffffffLL);
    int hi = (int)(b >> 32);
    // old = self: lanes with invalid source keep own value (no-op for min)
    int tlo = __builtin_amdgcn_update_dpp(lo, lo, CTRL, RM, 0xf, false);
    int thi = __builtin_amdgcn_update_dpp(hi, hi, CTRL, RM, 0xf, false);
    double t = __longlong_as_double(((long long)thi << 32) | (unsigned int)tlo);
    return fmin(x, t);   // v_min_f64; NaNs impossible here
}

__device__ __forceinline__ double wave_min_f64(double val) {
    double r = val;
    r = dpp_min_f64<0x111, 0xf>(r);  // row_shr:1
    r = dpp_min_f64<0x112, 0xf>(r);  // row_shr:2
    r = dpp_min_f64<0x114, 0xf>(r);  // row_shr:4
    r = dpp_min_f64<0x118, 0xf>(r);  // row_shr:8
    r = dpp_min_f64<0x142, 0xa>(r);  // row_bcast:15 -> rows 1,3
    r = dpp_min_f64<0x143, 0xc>(r);  // row_bcast:31 -> rows 2,3
    return readlane_f64(r, 63);      // lane 63 holds the full min
}

__global__ __launch_bounds__(64) void lsa_kernel(
    const float* __restrict__ C,   // [BS*NQ, NTOT]
    float*       __restrict__ pi,  // [BS, NPAIR]
    float*       __restrict__ ti)  // [BS, NPAIR]
{
    const int blk = blockIdx.x;          // 0..175
    const int b = blk / GN, g = blk % GN;
    const int lane = threadIdx.x;        // 0..63

    __shared__ double lcost[NROW * MCOL];   // [row i][col j], row-major

    // Coalesced global read (i fastest -> consecutive C addresses).
    for (int k = lane; k < NROW * MCOL; k += 64) {
        int i = k % NROW, j = k / NROW;
        lcost[i * MCOL + j] =
            (double)C[((long)(b * NQ + g * GQ + j)) * NTOT + (b * NT + i)];
    }
    __syncthreads();   // only barrier in the kernel (single wave otherwise)

    const bool incol = (lane >= 1 && lane <= MCOL);
    const int cidx = incol ? lane - 1 : 0;
    const double INF = __builtin_inf();

    int    pcol_l = 0;    // p[lane]   (0 = unassigned)
    double urow_l = 0.0;  // u[p[lane]]
    double v_l    = 0.0;  // v[lane]
    int    way_l  = 0;
    double minv_l = INF;
    bool   used_l = false;

    for (int i = 1; i <= NROW; ++i) {
        if (lane == 0) { pcol_l = i; urow_l = 0.0; }  // p[0]=i, u[i]=0 (fresh row)
        minv_l = INF;
        used_l = false;
        int j0 = 0;
        int i0 = i;            // p[j0] at loop top
        double u_i0 = 0.0;     // u[i0]

        for (int guard = 0; guard <= MCOL + 1; ++guard) {
            used_l = used_l || (lane == j0);

            double cd  = lcost[(i0 - 1) * MCOL + cidx];
            bool freel = incol && !used_l;
            double cur = (cd - u_i0) - v_l;           // (cost - u) - v, ref order
            bool upd   = freel && (cur < minv_l);
            minv_l = upd ? cur : minv_l;
            way_l  = upd ? j0  : way_l;

            double val   = freel ? minv_l : INF;
            double delta = wave_min_f64(val);
            unsigned long long mm = __ballot(freel && (minv_l == delta));
            int j1 = (int)__builtin_ctzll(mm);        // lowest lane = np.argmin

            // updates (used set includes j0, excludes j1 — matches reference)
            urow_l = used_l ? urow_l + delta : urow_l;
            v_l    = used_l ? v_l - delta    : v_l;
            minv_l = freel  ? minv_l - delta : minv_l;

            int i0n = __builtin_amdgcn_readlane(pcol_l, j1);
            j0 = j1;
            if (i0n == 0) break;
            i0   = i0n;
            u_i0 = readlane_f64(urow_l, j1);          // after updates, as ref
        }

        // augment back-walk: p[j]=p[way[j]], moving urow with pcol
        int j = j0;
        while (j != 0) {
            int wj   = __builtin_amdgcn_readlane(way_l, j);
            int pr   = __builtin_amdgcn_readlane(pcol_l, wj);
            double ur = readlane_f64(urow_l, wj);
            if (lane == j) { pcol_l = pr; urow_l = ur; }
            j = wj;
        }
    }

    // Extraction: ascending column (query) order == reference's row-sorted
    // order after the transpose swap. Parallel rank via ballot+popcount.
    unsigned long long asg = __ballot(incol && pcol_l != 0);
    if (incol && pcol_l != 0) {
        int k = __popcll(asg & ((1ull << lane) - 1));
        float* pib = pi + ((long)b * NPAIR + (long)g * NT);
        float* tib = ti + ((long)b * NPAIR + (long)g * NT);
        pib[k] = (float)(g * GQ + cidx);
        tib[k] = (float)(pcol_l - 1);
    }
}

extern "C" void kernel_launch(void* const* d_in, const int* in_sizes, int n_in,
                              void* d_out, int out_size, void* d_ws, size_t ws_size,
                              hipStream_t stream) {
    const float* logits = (const float*)d_in[0];   // [16,550,91] f32
    const float* pboxes = (const float*)d_in[1];   // [16,550,6] f32
    const int*   labels = (const int*)d_in[2];     // [16,48] i32
    const float* tboxes = (const float*)d_in[3];   // [16,48,6] f32

    float* out = (float*)d_out;
    float* C  = out;                               // 16*550*768
    float* pi = out + (long)BS * NQ * NTOT;
    float* ti = pi + (long)BS * NPAIR;

    long total = (long)BS * NQ * NTOT;
    int blocks = (int)((total + 255) / 256);

    const size_t tab_bytes = (size_t)BS * NQ * NC * sizeof(float);  // 3.2 MB
    if (ws_size >= tab_bytes) {
        float* tab = (float*)d_ws;
        int tblocks = (BS * NQ * NC + 255) / 256;
        focal_table_kernel<<<tblocks, 256, 0, stream>>>(logits, tab);
        cost_kernel<true><<<blocks, 256, 0, stream>>>(tab, logits, pboxes, labels, tboxes, C);
    } else {
        cost_kernel<false><<<blocks, 256, 0, stream>>>(nullptr, logits, pboxes, labels, tboxes, C);
    }
    lsa_kernel<<<BS * GN, 64, 0, stream>>>(C, pi, ti);
}

// Round 3
// 191.682 us; speedup vs baseline: 2.3979x; 1.1106x over previous
//
#include <hip/hip_runtime.h>
#include <math.h>

// Problem constants (setup_inputs: bs=16, nq=550, nc=91, nt=48, group_num=11)
#define BS 16
#define NQ 550
#define NC 91
#define NT 48
#define GN 11
#define GQ 50                 // queries per group
#define NTOT (BS * NT)        // 768
#define NROW 48               // LSA rows (targets) after reference transpose
#define MCOL 50               // LSA cols (queries)
#define NPAIR (GN * NT)       // 528
#define NLSA (BS * GN)        // 176 LSA blocks

// ---------------- focal (class) cost: f64 exp/log, rounded once to f32 ------
__device__ __forceinline__ float sigmoid_f32(float x) {
    double e = exp(-(double)x);
    return (float)(1.0 / (1.0 + e));
}
__device__ __forceinline__ float log_f32(float x) {
    return (float)log((double)x);
}
__device__ __forceinline__ float focal_cost(float x) {
    float prob = sigmoid_f32(x);
    float q = __fsub_rn(1.0f, prob);
    const float EPSF = 1e-8f;
    float lneg = log_f32(__fadd_rn(q, EPSF));
    float lpos = log_f32(__fadd_rn(prob, EPSF));
    float p2 = __fmul_rn(prob, prob);
    float q2 = __fmul_rn(q, q);
    float neg = __fmul_rn(__fmul_rn(0.75f, p2), -lneg);
    float pos = __fmul_rn(__fmul_rn(0.25f, q2), -lpos);
    return __fsub_rn(pos, neg);
}

// Table: tab[p*NC + c]. 800,800 transcendental triples instead of 6.76M.
__global__ __launch_bounds__(256) void focal_table_kernel(
    const float* __restrict__ logits, float* __restrict__ tab) {
    int idx = blockIdx.x * 256 + threadIdx.x;
    if (idx >= BS * NQ * NC) return;
    tab[idx] = focal_cost(logits[idx]);
}

// ---------------- one C element, f32 __f*_rn in reference association order --
// Used by BOTH the cost blocks and the LSA tile fill -> bit-identical values.
template <bool USE_TAB>
__device__ __forceinline__ float cost_element(
    const float* __restrict__ tab, const float* __restrict__ logits,
    const float* __restrict__ pboxes, const int* __restrict__ labels,
    const float* __restrict__ tboxes, int p, int t)
{
    const float* pb = pboxes + (long)p * 6;
    float pcx = pb[0], pcy = pb[1], pl = pb[2], pr = pb[3], ptt = pb[4], pbo = pb[5];
    const float* tb = tboxes + (long)t * 6;
    float tcx = tb[0], tcy = tb[1], tl = tb[2], tr = tb[3], ttt = tb[4], tbo = tb[5];

    float c3d = __fadd_rn(fabsf(__fsub_rn(pcx, tcx)), fabsf(__fsub_rn(pcy, tcy)));
    float cbb = __fadd_rn(
                  __fadd_rn(
                    __fadd_rn(fabsf(__fsub_rn(pl, tl)), fabsf(__fsub_rn(pr, tr))),
                    fabsf(__fsub_rn(ptt, ttt))),
                  fabsf(__fsub_rn(pbo, tbo)));

    float px1 = __fsub_rn(pcx, pl), py1 = __fsub_rn(pcy, ptt);
    float px2 = __fadd_rn(pcx, pr), py2 = __fadd_rn(pcy, pbo);
    float tx1 = __fsub_rn(tcx, tl), ty1 = __fsub_rn(tcy, ttt);
    float tx2 = __fadd_rn(tcx, tr), ty2 = __fadd_rn(tcy, tbo);

    float area1 = __fmul_rn(__fsub_rn(px2, px1), __fsub_rn(py2, py1));
    float area2 = __fmul_rn(__fsub_rn(tx2, tx1), __fsub_rn(ty2, ty1));
    float ltx = fmaxf(px1, tx1), lty = fmaxf(py1, ty1);
    float rbx = fminf(px2, tx2), rby = fminf(py2, ty2);
    float wx = fmaxf(__fsub_rn(rbx, ltx), 0.0f);
    float wy = fmaxf(__fsub_rn(rby, lty), 0.0f);
    float inter = __fmul_rn(wx, wy);
    float uni = __fsub_rn(__fadd_rn(area1, area2), inter);
    float iou = __fdiv_rn(inter, uni);
    float ex1 = fminf(px1, tx1), ey1 = fminf(py1, ty1);
    float ex2 = fmaxf(px2, tx2), ey2 = fmaxf(py2, ty2);
    float ew = fmaxf(__fsub_rn(ex2, ex1), 0.0f);
    float eh = fmaxf(__fsub_rn(ey2, ey1), 0.0f);
    float earea = __fmul_rn(ew, eh);
    float giou = __fsub_rn(iou, __fdiv_rn(__fsub_rn(earea, uni), earea));
    float cgiou = -giou;

    int c = labels[t];
    float cclass;
    if (USE_TAB) cclass = tab[(long)p * NC + c];
    else         cclass = focal_cost(logits[(long)p * NC + c]);

    float out = __fmul_rn(5.0f, cbb);
    out = __fadd_rn(out, __fmul_rn(10.0f, c3d));
    out = __fadd_rn(out, __fmul_rn(2.0f, cclass));
    out = __fadd_rn(out, __fmul_rn(2.0f, cgiou));
    return out;
}

// ---------------- cross-lane f64 helpers ------------------------------------
__device__ __forceinline__ double readlane_f64(double x, int l) {
    long long b = __double_as_longlong(x);
    int lo = __builtin_amdgcn_readlane((int)(b & 0xffffffffLL), l);
    int hi = __builtin_amdgcn_readlane((int)(b >> 32), l);
    return __longlong_as_double(((long long)hi << 32) | (unsigned int)lo);
}

template <int CTRL, int RM>
__device__ __forceinline__ double dpp_min_f64(double x) {
    long long b = __double_as_longlong(x);
    int lo = (int)(b & 0xffffffffLL);
    int hi = (int)(b >> 32);
    int tlo = __builtin_amdgcn_update_dpp(lo, lo, CTRL, RM, 0xf, false);
    int thi = __builtin_amdgcn_update_dpp(hi, hi, CTRL, RM, 0xf, false);
    double t = __longlong_as_double(((long long)thi << 32) | (unsigned int)tlo);
    return fmin(x, t);   // v_min_f64; NaNs impossible here
}

__device__ __forceinline__ double wave_min_f64(double val) {
    double r = val;
    r = dpp_min_f64<0x111, 0xf>(r);  // row_shr:1
    r = dpp_min_f64<0x112, 0xf>(r);  // row_shr:2
    r = dpp_min_f64<0x114, 0xf>(r);  // row_shr:4
    r = dpp_min_f64<0x118, 0xf>(r);  // row_shr:8
    r = dpp_min_f64<0x142, 0xa>(r);  // row_bcast:15
    r = dpp_min_f64<0x143, 0xc>(r);  // row_bcast:31
    return readlane_f64(r, 63);      // lane 63 holds the full min
}

// ---------------- mega kernel: blocks [0,176) = LSA, rest = cost matrix -----
// LSA blocks compute their own 48x50 tile (bit-identical to C) so the solve
// does NOT depend on the global C write -> cost blocks overlap with the
// latency-bound solves. JV shortest-augmenting-path, all cross-lane state in
// wave-0 registers (see round-2 notes); f64 ops in reference order ->
// bit-exact decisions vs numpy.
template <bool USE_TAB>
__global__ __launch_bounds__(256) void mega_kernel(
    const float* __restrict__ tab,
    const float* __restrict__ logits,
    const float* __restrict__ pboxes,
    const int*   __restrict__ labels,
    const float* __restrict__ tboxes,
    float*       __restrict__ C,
    float*       __restrict__ pi,
    float*       __restrict__ ti)
{
    if (blockIdx.x >= NLSA) {
        long idx = (long)(blockIdx.x - NLSA) * 256 + threadIdx.x;
        if (idx >= (long)BS * NQ * NTOT) return;
        int t = (int)(idx % NTOT);
        int p = (int)(idx / NTOT);
        C[idx] = cost_element<USE_TAB>(tab, logits, pboxes, labels, tboxes, p, t);
        return;
    }

    // ---- LSA block ----
    const int blk = blockIdx.x;          // 0..175
    const int b = blk / GN, g = blk % GN;
    const int tid = threadIdx.x;

    __shared__ double lcost[NROW * MCOL];   // [row i][col j]

    // All 256 threads fill the tile (2400 elements), then waves 1-3 exit.
    for (int k = tid; k < NROW * MCOL; k += 256) {
        int i = k % NROW, j = k / NROW;
        float cf = cost_element<USE_TAB>(tab, logits, pboxes, labels, tboxes,
                                         b * NQ + g * GQ + j, b * NT + i);
        lcost[i * MCOL + j] = (double)cf;
    }
    __syncthreads();   // last barrier; waves 1-3 exit below
    if (tid >= 64) return;

    const int lane = tid;
    const bool incol = (lane >= 1 && lane <= MCOL);
    const int cidx = incol ? lane - 1 : 0;
    const double INF = __builtin_inf();

    int    pcol_l = 0;    // p[lane]   (0 = unassigned)
    double urow_l = 0.0;  // u[p[lane]]
    double v_l    = 0.0;  // v[lane]
    int    way_l  = 0;
    double minv_l = INF;
    bool   used_l = false;

    for (int i = 1; i <= NROW; ++i) {
        if (lane == 0) { pcol_l = i; urow_l = 0.0; }
        minv_l = INF;
        used_l = false;
        int j0 = 0;
        int i0 = i;            // p[j0]
        double u_i0 = 0.0;     // u[i0]

        for (int guard = 0; guard <= MCOL + 1; ++guard) {
            used_l = used_l || (lane == j0);

            double cd  = lcost[(i0 - 1) * MCOL + cidx];
            bool freel = incol && !used_l;
            double cur = (cd - u_i0) - v_l;           // (cost - u) - v, ref order
            bool upd   = freel && (cur < minv_l);
            minv_l = upd ? cur : minv_l;
            way_l  = upd ? j0  : way_l;

            double val   = freel ? minv_l : INF;
            double delta = wave_min_f64(val);
            unsigned long long mm = __ballot(freel && (minv_l == delta));
            int j1 = (int)__builtin_ctzll(mm);        // lowest lane = np.argmin

            urow_l = used_l ? urow_l + delta : urow_l;
            v_l    = used_l ? v_l - delta    : v_l;
            minv_l = freel  ? minv_l - delta : minv_l;

            int i0n = __builtin_amdgcn_readlane(pcol_l, j1);
            j0 = j1;
            if (i0n == 0) break;
            i0   = i0n;
            u_i0 = readlane_f64(urow_l, j1);
        }

        // augment back-walk: p[j]=p[way[j]], moving urow with pcol
        int j = j0;
        while (j != 0) {
            int wj    = __builtin_amdgcn_readlane(way_l, j);
            int pr    = __builtin_amdgcn_readlane(pcol_l, wj);
            double ur = readlane_f64(urow_l, wj);
            if (lane == j) { pcol_l = pr; urow_l = ur; }
            j = wj;
        }
    }

    // Extraction: ascending query order == reference order after transpose.
    unsigned long long asg = __ballot(incol && pcol_l != 0);
    if (incol && pcol_l != 0) {
        int k = __popcll(asg & ((1ull << lane) - 1));
        float* pib = pi + ((long)b * NPAIR + (long)g * NT);
        float* tib = ti + ((long)b * NPAIR + (long)g * NT);
        pib[k] = (float)(g * GQ + cidx);
        tib[k] = (float)(pcol_l - 1);
    }
}

extern "C" void kernel_launch(void* const* d_in, const int* in_sizes, int n_in,
                              void* d_out, int out_size, void* d_ws, size_t ws_size,
                              hipStream_t stream) {
    const float* logits = (const float*)d_in[0];   // [16,550,91] f32
    const float* pboxes = (const float*)d_in[1];   // [16,550,6] f32
    const int*   labels = (const int*)d_in[2];     // [16,48] i32
    const float* tboxes = (const float*)d_in[3];   // [16,48,6] f32

    float* out = (float*)d_out;
    float* C  = out;                               // 16*550*768
    float* pi = out + (long)BS * NQ * NTOT;
    float* ti = pi + (long)BS * NPAIR;

    long total = (long)BS * NQ * NTOT;
    int cost_blocks = (int)((total + 255) / 256);
    int mega_blocks = NLSA + cost_blocks;

    const size_t tab_bytes = (size_t)BS * NQ * NC * sizeof(float);  // 3.2 MB
    if (ws_size >= tab_bytes) {
        float* tab = (float*)d_ws;
        int tblocks = (BS * NQ * NC + 255) / 256;
        focal_table_kernel<<<tblocks, 256, 0, stream>>>(logits, tab);
        mega_kernel<true><<<mega_blocks, 256, 0, stream>>>(
            tab, logits, pboxes, labels, tboxes, C, pi, ti);
    } else {
        mega_kernel<false><<<mega_blocks, 256, 0, stream>>>(
            nullptr, logits, pboxes, labels, tboxes, C, pi, ti);
    }
}